// Round 1
// 64.084 us; speedup vs baseline: 1.0050x; 1.0050x over previous
//
#include <hip/hip_runtime.h>

// IndirectLearningDPD: GMP basis + complex matmul, factored into an 8-tap
// complex stencil, register-tiled 4 outputs/thread, no LDS.
//
// y[n] = sum_{d=0..3} x[n-d] * C_d(n-d), where for m = n-d:
//   C_d(m) = c[0+d]
//          + c[4+d]*a2[m]  + c[8+d]*a4[m]  + c[12+d]*a6[m]
//          + c[16+d]*a2[m-1] + c[20+d]*a2[m-2]
//          + c[24+d]*a4[m-1] + c[28+d]*a4[m-2]
//          + c[32+d]*a6[m-1] + c[36+d]*a6[m-2]
//          + c[40+d]*a2[m+1] + c[44+d]*a2[m+2]
//          + c[48+d]*a4[m+1] + c[52+d]*a4[m+2]
//          + c[56+d]*a6[m+1] + c[60+d]*a6[m+2]
// a2 = |x|^2 (even powers only, no sqrt); out-of-range positions contribute
// exact zeros (matches the reference's zero padding on both delay and
// lag/lead shifts — x is zero-extended, so powers of padded x are 0 too).
//
// ABI (verified previous session): out_size = 2*N floats, complex64 output
// PLANAR: out[0:N] = real, out[N:2N] = imag.
//
// R0 (this round): counters showed the timed path is dominated by a fixed
// 40.5 us harness fillBuffer (268 MB re-poison @83% HBM); kernel residual
// ~24 us vs a ~2 us roofline floor -> instruction overhead, not BW. This
// version: 4 outputs/thread, 16B/lane global loads (no LDS, no barrier),
// float4 stores, d-outer loop keeps per-tap coeffs in SGPRs.

constexpr int BLOCK = 256;
constexpr int ITEMS = 4;

__global__ __launch_bounds__(BLOCK) void dpd_gmp_kernel(
    const float* __restrict__ xr, const float* __restrict__ xi,
    const float* __restrict__ cr, const float* __restrict__ ci,
    float* __restrict__ out, int N, int out_size)
{
    const int gid = blockIdx.x * BLOCK + threadIdx.x;
    const int n0  = gid * ITEMS;               // first output of this thread
    if (n0 >= N) return;

    // Register window: wr[q] = x_real[n0 - 8 + q], q in [0,16).
    // Needed: q in [3,13] for |x|^2 powers, q in [5,11] for x itself.
    // q 0..2 and 14..15 are loaded for alignment but never read.
    float wr[16], wi[16];
    const int m0 = n0 - 8;                     // multiple of 4 -> 16B aligned
    if (m0 >= 0 && m0 + 16 <= N) {
        const float4* r4 = reinterpret_cast<const float4*>(xr + m0);
        const float4* i4 = reinterpret_cast<const float4*>(xi + m0);
#pragma unroll
        for (int q = 0; q < 4; ++q) {
            reinterpret_cast<float4*>(wr)[q] = r4[q];
            reinterpret_cast<float4*>(wi)[q] = i4[q];
        }
    } else {
        // First/last couple of threads only: element-wise with zero padding.
#pragma unroll
        for (int q = 0; q < 16; ++q) {
            int m = m0 + q;
            bool ok = (m >= 0) && (m < N);
            wr[q] = ok ? xr[m] : 0.0f;
            wi[q] = ok ? xi[m] : 0.0f;
        }
    }

    // |x|^2, |x|^4, |x|^6 at q = 3..13 (constant indices after unroll ->
    // everything stays in registers).
    float p2[14], p4[14], p6[14];
#pragma unroll
    for (int q = 3; q <= 13; ++q) {
        float s = wr[q] * wr[q] + wi[q] * wi[q];
        p2[q] = s;
        p4[q] = s * s;
        p6[q] = p4[q] * s;
    }

    float yr[ITEMS] = {0.0f, 0.0f, 0.0f, 0.0f};
    float yi[ITEMS] = {0.0f, 0.0f, 0.0f, 0.0f};

#pragma unroll
    for (int d = 0; d < 4; ++d) {
        // 32 wave-uniform coefficients for this tap -> scalar loads, reused
        // across the 4 outputs below.
        const float c0r  = cr[ 0 + d], c0i  = ci[ 0 + d];
        const float c1r  = cr[ 4 + d], c1i  = ci[ 4 + d];
        const float c2r  = cr[ 8 + d], c2i  = ci[ 8 + d];
        const float c3r  = cr[12 + d], c3i  = ci[12 + d];
        const float c4r  = cr[16 + d], c4i  = ci[16 + d];
        const float c5r  = cr[20 + d], c5i  = ci[20 + d];
        const float c6r  = cr[24 + d], c6i  = ci[24 + d];
        const float c7r  = cr[28 + d], c7i  = ci[28 + d];
        const float c8r  = cr[32 + d], c8i  = ci[32 + d];
        const float c9r  = cr[36 + d], c9i  = ci[36 + d];
        const float cAr  = cr[40 + d], cAi  = ci[40 + d];
        const float cBr  = cr[44 + d], cBi  = ci[44 + d];
        const float cCr  = cr[48 + d], cCi  = ci[48 + d];
        const float cDr  = cr[52 + d], cDi  = ci[52 + d];
        const float cEr  = cr[56 + d], cEi  = ci[56 + d];
        const float cFr  = cr[60 + d], cFi  = ci[60 + d];

#pragma unroll
        for (int j = 0; j < ITEMS; ++j) {
            const int i = 8 + j - d;           // window index of m = n0+j-d
            float Cr = c0r;
            float Ci = c0i;
            Cr = fmaf(c1r, p2[i],     Cr);  Ci = fmaf(c1i, p2[i],     Ci);
            Cr = fmaf(c2r, p4[i],     Cr);  Ci = fmaf(c2i, p4[i],     Ci);
            Cr = fmaf(c3r, p6[i],     Cr);  Ci = fmaf(c3i, p6[i],     Ci);
            Cr = fmaf(c4r, p2[i - 1], Cr);  Ci = fmaf(c4i, p2[i - 1], Ci);
            Cr = fmaf(c5r, p2[i - 2], Cr);  Ci = fmaf(c5i, p2[i - 2], Ci);
            Cr = fmaf(c6r, p4[i - 1], Cr);  Ci = fmaf(c6i, p4[i - 1], Ci);
            Cr = fmaf(c7r, p4[i - 2], Cr);  Ci = fmaf(c7i, p4[i - 2], Ci);
            Cr = fmaf(c8r, p6[i - 1], Cr);  Ci = fmaf(c8i, p6[i - 1], Ci);
            Cr = fmaf(c9r, p6[i - 2], Cr);  Ci = fmaf(c9i, p6[i - 2], Ci);
            Cr = fmaf(cAr, p2[i + 1], Cr);  Ci = fmaf(cAi, p2[i + 1], Ci);
            Cr = fmaf(cBr, p2[i + 2], Cr);  Ci = fmaf(cBi, p2[i + 2], Ci);
            Cr = fmaf(cCr, p4[i + 1], Cr);  Ci = fmaf(cCi, p4[i + 1], Ci);
            Cr = fmaf(cDr, p4[i + 2], Cr);  Ci = fmaf(cDi, p4[i + 2], Ci);
            Cr = fmaf(cEr, p6[i + 1], Cr);  Ci = fmaf(cEi, p6[i + 1], Ci);
            Cr = fmaf(cFr, p6[i + 2], Cr);  Ci = fmaf(cFi, p6[i + 2], Ci);

            // y[n0+j] += x[m] * C_d(m); x zero-staged for m<0 kills the
            // whole column incl. the order-1 term (matches reference pad).
            yr[j] = fmaf(wr[i],  Cr, yr[j]);
            yr[j] = fmaf(-wi[i], Ci, yr[j]);
            yi[j] = fmaf(wr[i],  Ci, yi[j]);
            yi[j] = fmaf(wi[i],  Cr, yi[j]);
        }
    }

    // PLANAR complex64 output: out[0:N] = real, out[N:2N] = imag.
    if (n0 + ITEMS <= N && N + n0 + ITEMS <= out_size) {
        *reinterpret_cast<float4*>(out + n0) =
            make_float4(yr[0], yr[1], yr[2], yr[3]);
        *reinterpret_cast<float4*>(out + N + n0) =
            make_float4(yi[0], yi[1], yi[2], yi[3]);
    } else {
#pragma unroll
        for (int j = 0; j < ITEMS; ++j) {
            int n = n0 + j;
            if (n < N) {
                if (n < out_size)     out[n]     = yr[j];
                if (N + n < out_size) out[N + n] = yi[j];
            }
        }
    }
}

extern "C" void kernel_launch(void* const* d_in, const int* in_sizes, int n_in,
                              void* d_out, int out_size, void* d_ws, size_t ws_size,
                              hipStream_t stream) {
    const float* xr = (const float*)d_in[0];
    const float* xi = (const float*)d_in[1];
    const float* cr = (const float*)d_in[2];
    const float* ci = (const float*)d_in[3];
    float* out = (float*)d_out;

    const int N = in_sizes[0];  // B*S flattened signal length
    const int elems_per_block = BLOCK * ITEMS;
    const int grid = (N + elems_per_block - 1) / elems_per_block;
    dpd_gmp_kernel<<<grid, BLOCK, 0, stream>>>(xr, xi, cr, ci, out, N, out_size);
}